// Round 3
// baseline (522.932 us; speedup 1.0000x reference)
//
#include <hip/hip_runtime.h>
#include <hip/hip_bf16.h>
#include <hip/hip_fp16.h>
#include <math.h>

#define B_ 64
#define D_ 128
#define LC 1024
#define LQ 256
#define NEG_INF_ (-1e30f)
#define NSPLIT 8

// ---------------------------------------------------------------- ca = Ct @ w1
__global__ __launch_bounds__(256) void k_ca(const float* __restrict__ C,
                                            const float* __restrict__ w,
                                            float* __restrict__ ca) {
  int t = blockIdx.x * 256 + threadIdx.x;  // over B_*LC
  int b = t >> 10, i = t & (LC - 1);
  const float* Cp = C + (size_t)b * D_ * LC + i;
  float acc = 0.f;
#pragma unroll 8
  for (int dd = 0; dd < D_; ++dd) acc += Cp[(size_t)dd * LC] * w[dd];
  ca[t] = acc;
}

// ---------------------------------------------------------------- qb = Qt @ w2
__global__ __launch_bounds__(256) void k_qb(const float* __restrict__ Q,
                                            const float* __restrict__ w,
                                            float* __restrict__ qb) {
  int t = blockIdx.x * 256 + threadIdx.x;  // over B_*LQ
  int b = t >> 8, j = t & (LQ - 1);
  const float* Qp = Q + (size_t)b * D_ * LQ + j;
  float acc = 0.f;
#pragma unroll 8
  for (int dd = 0; dd < D_; ++dd) acc += Qp[(size_t)dd * LQ] * w[D_ + dd];
  qb[t] = acc;
}

// ------------------- S[b,i,j] = ca[i]+qb[j]+sum_d C*w3*Q  (stored as fp16)
__global__ __launch_bounds__(256) void k_S(const float* __restrict__ C,
                                           const float* __restrict__ Q,
                                           const float* __restrict__ w,
                                           const float* __restrict__ ca,
                                           const float* __restrict__ qb,
                                           __half* __restrict__ S) {
  __shared__ float Cs[32][68];
  __shared__ float Qs[32][68];
  int b = blockIdx.z;
  int i0 = blockIdx.y * 64;
  int j0 = blockIdx.x * 64;
  int t = threadIdx.x;
  int tj = t & 15, ti = t >> 4;
  float acc[4][4] = {};
  for (int d0 = 0; d0 < D_; d0 += 32) {
    __syncthreads();
#pragma unroll
    for (int r = 0; r < 8; ++r) {
      int idx = r * 256 + t;
      int kk = idx >> 6, col = idx & 63;
      Cs[kk][col] = C[(size_t)b * D_ * LC + (size_t)(d0 + kk) * LC + i0 + col] * w[2 * D_ + d0 + kk];
      Qs[kk][col] = Q[(size_t)b * D_ * LQ + (size_t)(d0 + kk) * LQ + j0 + col];
    }
    __syncthreads();
#pragma unroll
    for (int kk = 0; kk < 32; ++kk) {
      float cv[4], qv[4];
      *(float4*)cv = *(const float4*)&Cs[kk][ti * 4];
      *(float4*)qv = *(const float4*)&Qs[kk][tj * 4];
#pragma unroll
      for (int ii = 0; ii < 4; ++ii)
#pragma unroll
        for (int jj = 0; jj < 4; ++jj) acc[ii][jj] += cv[ii] * qv[jj];
    }
  }
  float qv4[4];
  *(float4*)qv4 = *(const float4*)&qb[b * LQ + j0 + tj * 4];
#pragma unroll
  for (int ii = 0; ii < 4; ++ii) {
    int i = i0 + ti * 4 + ii;
    float cav = ca[b * LC + i];
    __half h[4];
    h[0] = __float2half(acc[ii][0] + cav + qv4[0]);
    h[1] = __float2half(acc[ii][1] + cav + qv4[1]);
    h[2] = __float2half(acc[ii][2] + cav + qv4[2]);
    h[3] = __float2half(acc[ii][3] + cav + qv4[3]);
    *(ushort4*)&S[((size_t)b * LC + i) * LQ + j0 + tj * 4] = *(ushort4*)h;
  }
}

// ------------------------------- row softmax stats (axis=2, masked by qmask)
__global__ __launch_bounds__(256) void k_rowstats(const __half* __restrict__ S,
                                                  const float* __restrict__ qmask,
                                                  float* __restrict__ m1,
                                                  float* __restrict__ l1) {
  int wave = threadIdx.x >> 6, lane = threadIdx.x & 63;
  int row = blockIdx.x * 4 + wave;  // over B_*LC
  int b = row >> 10;
  ushort4 hv = *(const ushort4*)&S[(size_t)row * LQ + lane * 4];
  float sv[4], qm[4];
  sv[0] = __half2float(*(__half*)&hv.x);
  sv[1] = __half2float(*(__half*)&hv.y);
  sv[2] = __half2float(*(__half*)&hv.z);
  sv[3] = __half2float(*(__half*)&hv.w);
  *(float4*)qm = *(const float4*)&qmask[b * LQ + lane * 4];
#pragma unroll
  for (int k = 0; k < 4; ++k) sv[k] += (1.0f - qm[k]) * NEG_INF_;
  float m = fmaxf(fmaxf(sv[0], sv[1]), fmaxf(sv[2], sv[3]));
#pragma unroll
  for (int off = 32; off >= 1; off >>= 1) m = fmaxf(m, __shfl_xor(m, off));
  float e = expf(sv[0] - m) + expf(sv[1] - m) + expf(sv[2] - m) + expf(sv[3] - m);
#pragma unroll
  for (int off = 32; off >= 1; off >>= 1) e += __shfl_xor(e, off);
  if (lane == 0) { m1[row] = m; l1[row] = e; }
}

// ------------------------- col softmax stats partial (axis=1, masked by cmask)
__global__ __launch_bounds__(256) void k_colpart(const __half* __restrict__ S,
                                                 const float* __restrict__ cmask,
                                                 float* __restrict__ pm,
                                                 float* __restrict__ pl) {
  int split = blockIdx.x, b = blockIdx.y;
  int j = threadIdx.x;
  int ibeg = split * (LC / NSPLIT);
  float m = -1e38f, l = 0.f;
  for (int i = ibeg; i < ibeg + LC / NSPLIT; ++i) {
    float cm = cmask[b * LC + i];
    float v = __half2float(S[((size_t)b * LC + i) * LQ + j]) + (1.0f - cm) * NEG_INF_;
    float nm = fmaxf(m, v);
    l = l * expf(m - nm) + expf(v - nm);
    m = nm;
  }
  pm[((size_t)b * NSPLIT + split) * LQ + j] = m;
  pl[((size_t)b * NSPLIT + split) * LQ + j] = l;
}

__global__ __launch_bounds__(256) void k_colfin(const float* __restrict__ pm,
                                                const float* __restrict__ pl,
                                                float* __restrict__ m2,
                                                float* __restrict__ l2) {
  int t = blockIdx.x * 256 + threadIdx.x;  // over B_*LQ
  int b = t >> 8, j = t & (LQ - 1);
  float m = -1e38f;
#pragma unroll
  for (int s = 0; s < NSPLIT; ++s) m = fmaxf(m, pm[((size_t)b * NSPLIT + s) * LQ + j]);
  float l = 0.f;
#pragma unroll
  for (int s = 0; s < NSPLIT; ++s)
    l += pl[((size_t)b * NSPLIT + s) * LQ + j] * expf(pm[((size_t)b * NSPLIT + s) * LQ + j] - m);
  m2[t] = m;
  l2[t] = l;
}

// ------------------------------------------- R[b,j,d] = sum_i S2[i,j]*C[b,d,i]
__global__ __launch_bounds__(256) void k_R(const __half* __restrict__ S,
                                           const float* __restrict__ C,
                                           const float* __restrict__ cmask,
                                           const float* __restrict__ m2,
                                           const float* __restrict__ l2,
                                           float* __restrict__ R) {
  __shared__ float m2s[64], il2s[64];
  __shared__ float Ps[32][68];
  __shared__ float Cs[32][132];
  int b = blockIdx.y;
  int j0 = blockIdx.x * 64;
  int t = threadIdx.x;
  if (t < 64) {
    m2s[t] = m2[b * LQ + j0 + t];
    il2s[t] = 1.0f / l2[b * LQ + j0 + t];
  }
  int tj = t & 15, td = t >> 4;
  float acc[4][8] = {};
  for (int i0 = 0; i0 < LC; i0 += 32) {
    __syncthreads();
#pragma unroll
    for (int r = 0; r < 8; ++r) {
      int idx = r * 256 + t;
      int kk = idx >> 6, jj = idx & 63;
      int i = i0 + kk;
      float cm = cmask[b * LC + i];
      float v = __half2float(S[((size_t)b * LC + i) * LQ + j0 + jj]) + (1.0f - cm) * NEG_INF_;
      Ps[kk][jj] = expf(v - m2s[jj]) * il2s[jj];
    }
#pragma unroll
    for (int r = 0; r < 16; ++r) {
      int idx = r * 256 + t;
      int dd = idx >> 5, kk = idx & 31;
      Cs[kk][dd] = C[(size_t)b * D_ * LC + (size_t)dd * LC + i0 + kk];
    }
    __syncthreads();
#pragma unroll
    for (int kk = 0; kk < 32; ++kk) {
      float p[4], c[8];
      *(float4*)p = *(const float4*)&Ps[kk][tj * 4];
      *(float4*)c = *(const float4*)&Cs[kk][td * 8];
      *(float4*)(c + 4) = *(const float4*)&Cs[kk][td * 8 + 4];
#pragma unroll
      for (int jj = 0; jj < 4; ++jj)
#pragma unroll
        for (int k = 0; k < 8; ++k) acc[jj][k] += p[jj] * c[k];
    }
  }
#pragma unroll
  for (int jj = 0; jj < 4; ++jj) {
    int j = j0 + tj * 4 + jj;
    size_t base = ((size_t)b * LQ + j) * D_ + td * 8;
    float4 r0 = make_float4(acc[jj][0], acc[jj][1], acc[jj][2], acc[jj][3]);
    float4 r1 = make_float4(acc[jj][4], acc[jj][5], acc[jj][6], acc[jj][7]);
    *(float4*)&R[base] = r0;
    *(float4*)&R[base + 4] = r1;
  }
}

// ------------- final: A = S1@Qt, Bm = S1@R, write [Ct | A | Ct*A | Ct*Bm]^T
__global__ __launch_bounds__(256) void k_final(const __half* __restrict__ S,
                                               const float* __restrict__ C,
                                               const float* __restrict__ Q,
                                               const float* __restrict__ R,
                                               const float* __restrict__ qmask,
                                               const float* __restrict__ m1,
                                               const float* __restrict__ l1,
                                               float* __restrict__ out) {
  __shared__ float m1s[64], il1s[64];
  __shared__ float P1s[32][68];
  __shared__ float Qs[32][132];
  __shared__ float Rs[32][132];
  int b = blockIdx.y;
  int i0 = blockIdx.x * 64;
  int t = threadIdx.x;
  if (t < 64) {
    m1s[t] = m1[b * LC + i0 + t];
    il1s[t] = 1.0f / l1[b * LC + i0 + t];
  }
  int ti = t & 15, td = t >> 4;
  float accA[4][8] = {}, accB[4][8] = {};
  for (int j0 = 0; j0 < LQ; j0 += 32) {
    __syncthreads();
#pragma unroll
    for (int r = 0; r < 8; ++r) {
      int idx = r * 256 + t;
      int jj = idx & 31, iL = idx >> 5;
      float qm = qmask[b * LQ + j0 + jj];
      float v = __half2float(S[((size_t)b * LC + i0 + iL) * LQ + j0 + jj]) + (1.0f - qm) * NEG_INF_;
      P1s[jj][iL] = expf(v - m1s[iL]) * il1s[iL];
    }
#pragma unroll
    for (int r = 0; r < 16; ++r) {
      int idx = r * 256 + t;
      int kk = idx & 31, dd = idx >> 5;
      Qs[kk][dd] = Q[(size_t)b * D_ * LQ + (size_t)dd * LQ + j0 + kk];
    }
#pragma unroll
    for (int r = 0; r < 16; ++r) {
      int idx = r * 256 + t;
      int dd = idx & 127, kk = idx >> 7;
      Rs[kk][dd] = R[((size_t)b * LQ + j0 + kk) * D_ + dd];
    }
    __syncthreads();
#pragma unroll
    for (int kk = 0; kk < 32; ++kk) {
      float p[4], q[8], rr[8];
      *(float4*)p = *(const float4*)&P1s[kk][ti * 4];
      *(float4*)q = *(const float4*)&Qs[kk][td * 8];
      *(float4*)(q + 4) = *(const float4*)&Qs[kk][td * 8 + 4];
      *(float4*)rr = *(const float4*)&Rs[kk][td * 8];
      *(float4*)(rr + 4) = *(const float4*)&Rs[kk][td * 8 + 4];
#pragma unroll
      for (int ii = 0; ii < 4; ++ii) {
#pragma unroll
        for (int k = 0; k < 8; ++k) {
          accA[ii][k] += p[ii] * q[k];
          accB[ii][k] += p[ii] * rr[k];
        }
      }
    }
  }
#pragma unroll
  for (int k = 0; k < 8; ++k) {
    int dd = td * 8 + k;
    size_t cbase = (size_t)b * D_ * LC + (size_t)dd * LC + i0 + ti * 4;
    float4 c4 = *(const float4*)&C[cbase];
    float4 a4 = make_float4(accA[0][k], accA[1][k], accA[2][k], accA[3][k]);
    float4 b4 = make_float4(accB[0][k], accB[1][k], accB[2][k], accB[3][k]);
    size_t obase = ((size_t)b * 4 * D_ + dd) * LC + i0 + ti * 4;
    *(float4*)&out[obase] = c4;
    *(float4*)&out[obase + (size_t)D_ * LC] = a4;
    *(float4*)&out[obase + (size_t)2 * D_ * LC] =
        make_float4(c4.x * a4.x, c4.y * a4.y, c4.z * a4.z, c4.w * a4.w);
    *(float4*)&out[obase + (size_t)3 * D_ * LC] =
        make_float4(c4.x * b4.x, c4.y * b4.y, c4.z * b4.z, c4.w * b4.w);
  }
}

extern "C" void kernel_launch(void* const* d_in, const int* in_sizes, int n_in,
                              void* d_out, int out_size, void* d_ws, size_t ws_size,
                              hipStream_t stream) {
  const float* C = (const float*)d_in[0];
  const float* Q = (const float*)d_in[1];
  const float* cmask = (const float*)d_in[2];
  const float* qmask = (const float*)d_in[3];
  const float* w = (const float*)d_in[4];
  float* out = (float*)d_out;
  float* ws = (float*)d_ws;

  // ws layout (small buffers first; S fp16 last). Total ~42 MB.
  float* ca = ws;                                   // B*LC          = 65536 f32
  float* qb = ca + (size_t)B_ * LC;                 // B*LQ          = 16384
  float* m1 = qb + (size_t)B_ * LQ;                 // B*LC
  float* l1 = m1 + (size_t)B_ * LC;                 // B*LC
  float* m2 = l1 + (size_t)B_ * LC;                 // B*LQ
  float* l2 = m2 + (size_t)B_ * LQ;                 // B*LQ
  float* pm = l2 + (size_t)B_ * LQ;                 // B*NSPLIT*LQ
  float* pl = pm + (size_t)B_ * NSPLIT * LQ;        // B*NSPLIT*LQ
  float* R = pl + (size_t)B_ * NSPLIT * LQ;         // B*LQ*D_       = 2M f32
  __half* S = (__half*)(R + (size_t)B_ * LQ * D_);  // B*LC*LQ       = 16M fp16 = 32 MB

  k_ca<<<(B_ * LC) / 256, 256, 0, stream>>>(C, w, ca);
  k_qb<<<(B_ * LQ) / 256, 256, 0, stream>>>(Q, w, qb);
  k_S<<<dim3(LQ / 64, LC / 64, B_), 256, 0, stream>>>(C, Q, w, ca, qb, S);
  k_rowstats<<<(B_ * LC) / 4, 256, 0, stream>>>(S, qmask, m1, l1);
  k_colpart<<<dim3(NSPLIT, B_), 256, 0, stream>>>(S, cmask, pm, pl);
  k_colfin<<<(B_ * LQ) / 256, 256, 0, stream>>>(pm, pl, m2, l2);
  k_R<<<dim3(LQ / 64, B_), 256, 0, stream>>>(S, C, cmask, m2, l2, R);
  k_final<<<dim3(LC / 64, B_), 256, 0, stream>>>(S, C, Q, R, qmask, m1, l1, out);
}

// Round 4
// 324.447 us; speedup vs baseline: 1.6118x; 1.6118x over previous
//
#include <hip/hip_runtime.h>
#include <math.h>

#define B_ 64
#define D_ 128
#define LC 1024
#define LQ 256
#define NEG_INF_ (-1e30f)
#define NSPLIT 8

typedef short bf16x8 __attribute__((ext_vector_type(8)));
typedef float f32x4 __attribute__((ext_vector_type(4)));
typedef _Float16 f16x8 __attribute__((ext_vector_type(8)));
typedef _Float16 f16x4 __attribute__((ext_vector_type(4)));

// round-to-nearest-even f32 -> bf16 bits
__device__ __forceinline__ unsigned short bf16b(float x) {
  unsigned u = __builtin_bit_cast(unsigned, x);
  u = (u + 0x7FFFu + ((u >> 16) & 1u)) >> 16;
  return (unsigned short)u;
}

// ---------------------------------------------------------------- ca = Ct @ w1
__global__ __launch_bounds__(256) void k_ca(const float* __restrict__ C,
                                            const float* __restrict__ w,
                                            float* __restrict__ ca) {
  int t = blockIdx.x * 256 + threadIdx.x;
  int b = t >> 10, i = t & (LC - 1);
  const float* Cp = C + (size_t)b * D_ * LC + i;
  float acc = 0.f;
#pragma unroll 8
  for (int dd = 0; dd < D_; ++dd) acc += Cp[(size_t)dd * LC] * w[dd];
  ca[t] = acc;
}

// ---------------------------------------------------------------- qb = Qt @ w2
__global__ __launch_bounds__(256) void k_qb(const float* __restrict__ Q,
                                            const float* __restrict__ w,
                                            float* __restrict__ qb) {
  int t = blockIdx.x * 256 + threadIdx.x;
  int b = t >> 8, j = t & (LQ - 1);
  const float* Qp = Q + (size_t)b * D_ * LQ + j;
  float acc = 0.f;
#pragma unroll 8
  for (int dd = 0; dd < D_; ++dd) acc += Qp[(size_t)dd * LQ] * w[D_ + dd];
  qb[t] = acc;
}

// ------------------------------------- Qt_bf[b][j][d] = bf16(Q[b][d][j])
__global__ __launch_bounds__(256) void k_qt(const float* __restrict__ Q,
                                            unsigned short* __restrict__ Qt) {
  __shared__ float ts[64][65];
  int b = blockIdx.z, d0 = blockIdx.y * 64, j0 = blockIdx.x * 64;
  int t = threadIdx.x;
  int jc = t & 15, dr = t >> 4;
#pragma unroll
  for (int ii = 0; ii < 4; ++ii) {
    int d = dr + 16 * ii;
    float4 v = *(const float4*)&Q[((size_t)b * D_ + d0 + d) * LQ + j0 + 4 * jc];
    ts[4 * jc + 0][d] = v.x;
    ts[4 * jc + 1][d] = v.y;
    ts[4 * jc + 2][d] = v.z;
    ts[4 * jc + 3][d] = v.w;
  }
  __syncthreads();
  int j = t >> 2, h = t & 3;
  unsigned short tmp[16];
#pragma unroll
  for (int k = 0; k < 16; ++k) tmp[k] = bf16b(ts[j][h * 16 + k]);
  size_t base = ((size_t)b * LQ + j0 + j) * D_ + d0 + h * 16;
  *(bf16x8*)&Qt[base] = *(bf16x8*)&tmp[0];
  *(bf16x8*)&Qt[base + 8] = *(bf16x8*)&tmp[8];
}

// ---- k_S: S[i][j] = ca[i]+qb[j]+ (C*w3)^T Q via MFMA; fused row stats (m1,l1)
__global__ __launch_bounds__(256, 3) void k_S(const float* __restrict__ C,
                                              const unsigned short* __restrict__ Qt,
                                              const float* __restrict__ w,
                                              const float* __restrict__ ca,
                                              const float* __restrict__ qb,
                                              const float* __restrict__ qmask,
                                              _Float16* __restrict__ S,
                                              float* __restrict__ m1,
                                              float* __restrict__ l1) {
  __shared__ unsigned short Asw[64 * 128];  // (C*w3) transposed [i][d], XOR-swizzled
  int b = blockIdx.y;
  int i0 = blockIdx.x * 64;
  int t = threadIdx.x;
  // stage A: read C rows (coalesced), scatter-transpose into LDS
  {
    int fc = t & 15, dr = t >> 4;
#pragma unroll
    for (int ii = 0; ii < 8; ++ii) {
      int d = dr + 16 * ii;
      float w3 = w[2 * D_ + d];
      float4 v = *(const float4*)&C[((size_t)b * D_ + d) * LC + i0 + 4 * fc];
      float vv[4] = {v.x, v.y, v.z, v.w};
#pragma unroll
      for (int m = 0; m < 4; ++m) {
        int i = 4 * fc + m;
        Asw[i * 128 + (d ^ ((i & 7) << 3))] = bf16b(vv[m] * w3);
      }
    }
  }
  __syncthreads();

  int w_id = t >> 6, l = t & 63;
  int sl = l >> 4, lj = l & 15;
  int irow = w_id * 16 + lj;  // A-frag row
  f32x4 acc[16];
#pragma unroll
  for (int jt = 0; jt < 16; ++jt) acc[jt] = (f32x4){0.f, 0.f, 0.f, 0.f};

#pragma unroll
  for (int kk = 0; kk < 4; ++kk) {
    bf16x8 af = *(const bf16x8*)&Asw[irow * 128 + ((kk * 32 + 8 * sl) ^ ((irow & 7) << 3))];
#pragma unroll
    for (int jt = 0; jt < 16; ++jt) {
      bf16x8 bf = *(const bf16x8*)&Qt[((size_t)b * LQ + jt * 16 + lj) * D_ + kk * 32 + 8 * sl];
      acc[jt] = __builtin_amdgcn_mfma_f32_16x16x32_bf16(af, bf, acc[jt], 0, 0, 0);
    }
  }

  // epilogue: add ca/qb, store fp16 S, fused row-softmax stats
  int ibase = i0 + w_id * 16 + 4 * sl;  // D rows: ibase..ibase+3
  float4 cav = *(const float4*)&ca[b * LC + ibase];
  float cavr[4] = {cav.x, cav.y, cav.z, cav.w};
#pragma unroll
  for (int jt = 0; jt < 16; ++jt) {
    int j = jt * 16 + lj;
    float qbv = qb[b * LQ + j];
    float qadd = (1.0f - qmask[b * LQ + j]) * NEG_INF_;
#pragma unroll
    for (int r = 0; r < 4; ++r) {
      float sval = acc[jt][r] + cavr[r] + qbv;
      S[((size_t)(b * LC + ibase + r)) * LQ + j] = (_Float16)sval;
      acc[jt][r] = sval + qadd;  // masked value for stats
    }
  }
#pragma unroll
  for (int r = 0; r < 4; ++r) {
    float m = -1e38f;
#pragma unroll
    for (int jt = 0; jt < 16; ++jt) m = fmaxf(m, acc[jt][r]);
#pragma unroll
    for (int off = 1; off <= 8; off <<= 1) m = fmaxf(m, __shfl_xor(m, off));
    float s = 0.f;
#pragma unroll
    for (int jt = 0; jt < 16; ++jt) s += __expf(acc[jt][r] - m);
#pragma unroll
    for (int off = 1; off <= 8; off <<= 1) s += __shfl_xor(s, off);
    if (lj == 0) {
      m1[b * LC + ibase + r] = m;
      l1[b * LC + ibase + r] = s;
    }
  }
}

// ------------------------- col softmax stats partial (axis=1, masked by cmask)
__global__ __launch_bounds__(256) void k_colpart(const _Float16* __restrict__ S,
                                                 const float* __restrict__ cmask,
                                                 float* __restrict__ pm,
                                                 float* __restrict__ pl) {
  int split = blockIdx.x, b = blockIdx.y;
  int j = threadIdx.x;
  int ibeg = split * (LC / NSPLIT);
  float m = -1e38f, lsum = 0.f;
  for (int i = ibeg; i < ibeg + LC / NSPLIT; ++i) {
    float cm = cmask[b * LC + i];
    float v = (float)S[((size_t)b * LC + i) * LQ + j] + (1.0f - cm) * NEG_INF_;
    float nm = fmaxf(m, v);
    lsum = lsum * __expf(m - nm) + __expf(v - nm);
    m = nm;
  }
  pm[((size_t)b * NSPLIT + split) * LQ + j] = m;
  pl[((size_t)b * NSPLIT + split) * LQ + j] = lsum;
}

__global__ __launch_bounds__(256) void k_colfin(const float* __restrict__ pm,
                                                const float* __restrict__ pl,
                                                float* __restrict__ m2,
                                                float* __restrict__ l2) {
  int t = blockIdx.x * 256 + threadIdx.x;
  int b = t >> 8, j = t & (LQ - 1);
  float m = -1e38f;
#pragma unroll
  for (int s = 0; s < NSPLIT; ++s) m = fmaxf(m, pm[((size_t)b * NSPLIT + s) * LQ + j]);
  float lsum = 0.f;
#pragma unroll
  for (int s = 0; s < NSPLIT; ++s)
    lsum += pl[((size_t)b * NSPLIT + s) * LQ + j] * __expf(pm[((size_t)b * NSPLIT + s) * LQ + j] - m);
  m2[t] = m;
  l2[t] = lsum;
}

// ---- k_R: Rt[d][j] = sum_i C[d][i] * P2[i][j]   (MFMA, P2 staged transposed)
__global__ __launch_bounds__(256, 4) void k_R(const _Float16* __restrict__ S,
                                              const float* __restrict__ C,
                                              const float* __restrict__ cmask,
                                              const float* __restrict__ m2,
                                              const float* __restrict__ l2,
                                              unsigned short* __restrict__ Rt) {
  __shared__ unsigned short Pt[2][32 * 32];  // [j][i] XOR-swizzled
  __shared__ float m2s[32], il2s[32];
  int b = blockIdx.y;
  int j0 = blockIdx.x * 32;
  int t = threadIdx.x;
  if (t < 32) {
    m2s[t] = m2[b * LQ + j0 + t];
    il2s[t] = 1.0f / l2[b * LQ + j0 + t];
  }
  __syncthreads();

  int iL = t >> 3, jc = t & 7;
  int w_id = t >> 6, l = t & 63;
  int sl = l >> 4, lj = l & 15;
  int wbase = w_id * 32;

  f32x4 acc[2][2];
#pragma unroll
  for (int dt = 0; dt < 2; ++dt)
#pragma unroll
    for (int jt = 0; jt < 2; ++jt) acc[dt][jt] = (f32x4){0.f, 0.f, 0.f, 0.f};

  // stage step 0
  {
    f16x4 sv = *(const f16x4*)&S[((size_t)(b * LC + iL)) * LQ + j0 + 4 * jc];
    float cmadd = (1.0f - cmask[b * LC + iL]) * NEG_INF_;
#pragma unroll
    for (int m = 0; m < 4; ++m) {
      int jl = 4 * jc + m;
      float p = __expf((float)sv[m] + cmadd - m2s[jl]) * il2s[jl];
      Pt[0][jl * 32 + (iL ^ ((jl & 3) << 3))] = bf16b(p);
    }
  }
  __syncthreads();

  for (int kt = 0; kt < 32; ++kt) {
    int cur = kt & 1;
    if (kt < 31) {
      int i0n = (kt + 1) * 32;
      f16x4 sv = *(const f16x4*)&S[((size_t)(b * LC + i0n + iL)) * LQ + j0 + 4 * jc];
      float cmadd = (1.0f - cmask[b * LC + i0n + iL]) * NEG_INF_;
#pragma unroll
      for (int m = 0; m < 4; ++m) {
        int jl = 4 * jc + m;
        float p = __expf((float)sv[m] + cmadd - m2s[jl]) * il2s[jl];
        Pt[cur ^ 1][jl * 32 + (iL ^ ((jl & 3) << 3))] = bf16b(p);
      }
    }
    // compute on buffer cur
    bf16x8 af[2];
#pragma unroll
    for (int dt = 0; dt < 2; ++dt) {
      int d = wbase + dt * 16 + lj;
      const float* cp = &C[((size_t)b * D_ + d) * LC + kt * 32 + 8 * sl];
      float4 c0 = *(const float4*)cp;
      float4 c1 = *(const float4*)(cp + 4);
      unsigned short ab[8] = {bf16b(c0.x), bf16b(c0.y), bf16b(c0.z), bf16b(c0.w),
                              bf16b(c1.x), bf16b(c1.y), bf16b(c1.z), bf16b(c1.w)};
      af[dt] = *(bf16x8*)ab;
    }
#pragma unroll
    for (int jt = 0; jt < 2; ++jt) {
      bf16x8 bfp = *(const bf16x8*)&Pt[cur][(jt * 16 + lj) * 32 + ((8 * sl) ^ ((lj & 3) << 3))];
#pragma unroll
      for (int dt = 0; dt < 2; ++dt)
        acc[dt][jt] = __builtin_amdgcn_mfma_f32_16x16x32_bf16(af[dt], bfp, acc[dt][jt], 0, 0, 0);
    }
    __syncthreads();
  }

#pragma unroll
  for (int dt = 0; dt < 2; ++dt)
#pragma unroll
    for (int jt = 0; jt < 2; ++jt)
#pragma unroll
      for (int r = 0; r < 4; ++r) {
        int d = wbase + dt * 16 + 4 * sl + r;
        int j = j0 + jt * 16 + lj;
        Rt[((size_t)b * D_ + d) * LQ + j] = bf16b(acc[dt][jt][r]);
      }
}

// ---- k_final: D1[d][i] = sum_j Q[d][j] P1[i][j]; D2 with Rt; direct stores
__global__ __launch_bounds__(256, 3) void k_final(const _Float16* __restrict__ S,
                                                  const float* __restrict__ C,
                                                  const float* __restrict__ Q,
                                                  const unsigned short* __restrict__ Rt,
                                                  const float* __restrict__ qmask,
                                                  const float* __restrict__ m1,
                                                  const float* __restrict__ l1,
                                                  float* __restrict__ out) {
  __shared__ unsigned short P_lds[2][64 * 32];  // [i][j] natural
  __shared__ float m1s[64], il1s[64], qadds[256];
  int b = blockIdx.y;
  int i0 = blockIdx.x * 64;
  int t = threadIdx.x;
  if (t < 64) {
    m1s[t] = m1[b * LC + i0 + t];
    il1s[t] = 1.0f / l1[b * LC + i0 + t];
  }
  qadds[t] = (1.0f - qmask[b * LQ + t]) * NEG_INF_;
  __syncthreads();

  int iL = t >> 2, jc = t & 3;
  int w_id = t >> 6, l = t & 63;
  int sl = l >> 4, lj = l & 15;
  int wbase = w_id * 32;
  float m1v = m1s[iL], il1v = il1s[iL];

  f32x4 accQ[2][4], accR[2][4];
#pragma unroll
  for (int dt = 0; dt < 2; ++dt)
#pragma unroll
    for (int it = 0; it < 4; ++it) {
      accQ[dt][it] = (f32x4){0.f, 0.f, 0.f, 0.f};
      accR[dt][it] = (f32x4){0.f, 0.f, 0.f, 0.f};
    }

  // stage step 0
  {
    f16x8 sv = *(const f16x8*)&S[((size_t)(b * LC + i0 + iL)) * LQ + 8 * jc];
    float qa[8];
    *(float4*)qa = *(const float4*)&qadds[8 * jc];
    *(float4*)(qa + 4) = *(const float4*)&qadds[8 * jc + 4];
    unsigned short pb[8];
#pragma unroll
    for (int e = 0; e < 8; ++e)
      pb[e] = bf16b(__expf((float)sv[e] + qa[e] - m1v) * il1v);
    *(bf16x8*)&P_lds[0][iL * 32 + 8 * jc] = *(bf16x8*)pb;
  }
  __syncthreads();

  for (int s = 0; s < 8; ++s) {
    int cur = s & 1;
    if (s < 7) {
      int j0n = (s + 1) * 32;
      f16x8 sv = *(const f16x8*)&S[((size_t)(b * LC + i0 + iL)) * LQ + j0n + 8 * jc];
      float qa[8];
      *(float4*)qa = *(const float4*)&qadds[j0n + 8 * jc];
      *(float4*)(qa + 4) = *(const float4*)&qadds[j0n + 8 * jc + 4];
      unsigned short pb[8];
#pragma unroll
      for (int e = 0; e < 8; ++e)
        pb[e] = bf16b(__expf((float)sv[e] + qa[e] - m1v) * il1v);
      *(bf16x8*)&P_lds[cur ^ 1][iL * 32 + 8 * jc] = *(bf16x8*)pb;
    }
    // compute on buffer cur; j-range = s*32..+31
    int j0c = s * 32;
    bf16x8 aQ[2], aR[2];
#pragma unroll
    for (int dt = 0; dt < 2; ++dt) {
      int d = wbase + dt * 16 + lj;
      const float* qp = &Q[((size_t)b * D_ + d) * LQ + j0c + 8 * sl];
      float4 q0 = *(const float4*)qp;
      float4 q1 = *(const float4*)(qp + 4);
      unsigned short ab[8] = {bf16b(q0.x), bf16b(q0.y), bf16b(q0.z), bf16b(q0.w),
                              bf16b(q1.x), bf16b(q1.y), bf16b(q1.z), bf16b(q1.w)};
      aQ[dt] = *(bf16x8*)ab;
      aR[dt] = *(const bf16x8*)&Rt[((size_t)b * D_ + d) * LQ + j0c + 8 * sl];
    }
#pragma unroll
    for (int it = 0; it < 4; ++it) {
      bf16x8 bP = *(const bf16x8*)&P_lds[cur][(it * 16 + lj) * 32 + 8 * sl];
#pragma unroll
      for (int dt = 0; dt < 2; ++dt) {
        accQ[dt][it] = __builtin_amdgcn_mfma_f32_16x16x32_bf16(aQ[dt], bP, accQ[dt][it], 0, 0, 0);
        accR[dt][it] = __builtin_amdgcn_mfma_f32_16x16x32_bf16(aR[dt], bP, accR[dt][it], 0, 0, 0);
      }
    }
    __syncthreads();
  }

  // epilogue: direct coalesced stores (cols = i contiguous across lanes)
#pragma unroll
  for (int dt = 0; dt < 2; ++dt)
#pragma unroll
    for (int it = 0; it < 4; ++it)
#pragma unroll
      for (int r = 0; r < 4; ++r) {
        int d = wbase + dt * 16 + 4 * sl + r;
        int gi = i0 + it * 16 + lj;
        float c = C[((size_t)b * D_ + d) * LC + gi];
        float a = accQ[dt][it][r];
        float bm = accR[dt][it][r];
        size_t ob = ((size_t)b * 512 + d) * LC + gi;
        out[ob] = c;
        out[ob + (size_t)128 * LC] = a;
        out[ob + (size_t)256 * LC] = c * a;
        out[ob + (size_t)384 * LC] = c * bm;
      }
}

extern "C" void kernel_launch(void* const* d_in, const int* in_sizes, int n_in,
                              void* d_out, int out_size, void* d_ws, size_t ws_size,
                              hipStream_t stream) {
  const float* C = (const float*)d_in[0];
  const float* Q = (const float*)d_in[1];
  const float* cmask = (const float*)d_in[2];
  const float* qmask = (const float*)d_in[3];
  const float* w = (const float*)d_in[4];
  float* out = (float*)d_out;
  float* ws = (float*)d_ws;

  // ws layout (~41.9 MB, proven-safe size): small f32 first, fp16/bf16 last
  float* ca = ws;                                    // B*LC
  float* qb = ca + (size_t)B_ * LC;                  // B*LQ
  float* m1 = qb + (size_t)B_ * LQ;                  // B*LC
  float* l1 = m1 + (size_t)B_ * LC;                  // B*LC
  float* m2 = l1 + (size_t)B_ * LC;                  // B*LQ
  float* l2 = m2 + (size_t)B_ * LQ;                  // B*LQ
  float* pm = l2 + (size_t)B_ * LQ;                  // B*NSPLIT*LQ
  float* pl = pm + (size_t)B_ * NSPLIT * LQ;         // B*NSPLIT*LQ
  unsigned short* Qt = (unsigned short*)(pl + (size_t)B_ * NSPLIT * LQ);  // B*LQ*D
  unsigned short* Rt = Qt + (size_t)B_ * LQ * D_;    // B*D*LQ
  _Float16* S = (_Float16*)(Rt + (size_t)B_ * D_ * LQ);  // B*LC*LQ fp16 (32MB)

  k_ca<<<(B_ * LC) / 256, 256, 0, stream>>>(C, w, ca);
  k_qb<<<(B_ * LQ) / 256, 256, 0, stream>>>(Q, w, qb);
  k_qt<<<dim3(LQ / 64, D_ / 64, B_), 256, 0, stream>>>(Q, Qt);
  k_S<<<dim3(LC / 64, B_), 256, 0, stream>>>(C, Qt, w, ca, qb, qmask, S, m1, l1);
  k_colpart<<<dim3(NSPLIT, B_), 256, 0, stream>>>(S, cmask, pm, pl);
  k_colfin<<<(B_ * LQ) / 256, 256, 0, stream>>>(pm, pl, m2, l2);
  k_R<<<dim3(LQ / 32, B_), 256, 0, stream>>>(S, C, cmask, m2, l2, Rt);
  k_final<<<dim3(LC / 64, B_), 256, 0, stream>>>(S, C, Q, Rt, qmask, m1, l1, out);
}

// Round 5
// 296.122 us; speedup vs baseline: 1.7659x; 1.0957x over previous
//
#include <hip/hip_runtime.h>
#include <math.h>

#define B_ 64
#define D_ 128
#define LC 1024
#define LQ 256
#define NEG_INF_ (-1e30f)
#define NBLK 16  // LC/64 column-partial splits

typedef short bf16x8 __attribute__((ext_vector_type(8)));
typedef float f32x4 __attribute__((ext_vector_type(4)));
typedef _Float16 f16x8 __attribute__((ext_vector_type(8)));
typedef _Float16 f16x4 __attribute__((ext_vector_type(4)));

// round-to-nearest-even f32 -> bf16 bits
__device__ __forceinline__ unsigned short bf16b(float x) {
  unsigned u = __builtin_bit_cast(unsigned, x);
  u = (u + 0x7FFFu + ((u >> 16) & 1u)) >> 16;
  return (unsigned short)u;
}

// ---- k_prep_q: Qt[b][j][d] = bf16(Q[b][d][j]);  qb[b][j] = sum_d Q[d][j]*w2[d]
__global__ __launch_bounds__(256) void k_prep_q(const float* __restrict__ Q,
                                                const float* __restrict__ w,
                                                unsigned short* __restrict__ Qt,
                                                float* __restrict__ qb) {
  __shared__ float ts[64][129];  // [j_local][d]
  __shared__ float qP[16][64];   // partial qb sums
  int b = blockIdx.y, j0 = blockIdx.x * 64;
  int t = threadIdx.x;
  int jc = t & 15, dr = t >> 4;
  float qpart[4] = {0.f, 0.f, 0.f, 0.f};
#pragma unroll
  for (int ii = 0; ii < 8; ++ii) {
    int d = dr + 16 * ii;
    float4 v = *(const float4*)&Q[((size_t)b * D_ + d) * LQ + j0 + 4 * jc];
    float w2 = w[D_ + d];
    ts[4 * jc + 0][d] = v.x;
    ts[4 * jc + 1][d] = v.y;
    ts[4 * jc + 2][d] = v.z;
    ts[4 * jc + 3][d] = v.w;
    qpart[0] += v.x * w2;
    qpart[1] += v.y * w2;
    qpart[2] += v.z * w2;
    qpart[3] += v.w * w2;
  }
#pragma unroll
  for (int m = 0; m < 4; ++m) qP[dr][4 * jc + m] = qpart[m];
  __syncthreads();
  if (t < 64) {
    float s = 0.f;
#pragma unroll
    for (int r = 0; r < 16; ++r) s += qP[r][t];
    qb[b * LQ + j0 + t] = s;
  }
  int j = t >> 2, h = t & 3;
  unsigned short tmp[32];
#pragma unroll
  for (int k = 0; k < 32; ++k) tmp[k] = bf16b(ts[j][h * 32 + k]);
  size_t base = ((size_t)b * LQ + j0 + j) * D_ + h * 32;
#pragma unroll
  for (int q = 0; q < 4; ++q) *(bf16x8*)&Qt[base + 8 * q] = *(bf16x8*)&tmp[8 * q];
}

// ---- k_S: S = ca(+fused) + qb + (C*w3)^T Q  (MFMA); fused row stats + col partials
__global__ __launch_bounds__(256, 3) void k_S(const float* __restrict__ C,
                                              const unsigned short* __restrict__ Qt,
                                              const float* __restrict__ w,
                                              const float* __restrict__ qb,
                                              const float* __restrict__ qmask,
                                              const float* __restrict__ cmask,
                                              _Float16* __restrict__ S,
                                              float* __restrict__ m1,
                                              float* __restrict__ l1,
                                              float* __restrict__ pm,
                                              float* __restrict__ pl) {
  __shared__ unsigned short Asw[64 * 128];  // (C*w3)^T [i][d], XOR-swizzled
  __shared__ float caP[16][64];             // ca partials
  __shared__ float ca_s[64];
  __shared__ float qadds[256];
  __shared__ float colM[4][256], colL[4][256];
  int b = blockIdx.y;
  int i0 = blockIdx.x * 64;
  int t = threadIdx.x;
  qadds[t] = (1.0f - qmask[b * LQ + t]) * NEG_INF_;
  // stage A: read C rows (coalesced), scatter-transpose into LDS; fuse ca partials
  {
    int fc = t & 15, dr = t >> 4;
    float cap[4] = {0.f, 0.f, 0.f, 0.f};
#pragma unroll
    for (int ii = 0; ii < 8; ++ii) {
      int d = dr + 16 * ii;
      float w1 = w[d];
      float w3 = w[2 * D_ + d];
      float4 v = *(const float4*)&C[((size_t)b * D_ + d) * LC + i0 + 4 * fc];
      float vv[4] = {v.x, v.y, v.z, v.w};
#pragma unroll
      for (int m = 0; m < 4; ++m) {
        int i = 4 * fc + m;
        Asw[i * 128 + (d ^ ((i & 7) << 3))] = bf16b(vv[m] * w3);
        cap[m] += vv[m] * w1;
      }
    }
#pragma unroll
    for (int m = 0; m < 4; ++m) caP[dr][4 * fc + m] = cap[m];
  }
  __syncthreads();
  if (t < 64) {
    float s = 0.f;
#pragma unroll
    for (int r = 0; r < 16; ++r) s += caP[r][t];
    ca_s[t] = s;
  }
  __syncthreads();

  int w_id = t >> 6, l = t & 63;
  int sl = l >> 4, lj = l & 15;
  int irow = w_id * 16 + lj;
  f32x4 acc[16];
#pragma unroll
  for (int jt = 0; jt < 16; ++jt) acc[jt] = (f32x4){0.f, 0.f, 0.f, 0.f};

#pragma unroll
  for (int kk = 0; kk < 4; ++kk) {
    bf16x8 af = *(const bf16x8*)&Asw[irow * 128 + ((kk * 32 + 8 * sl) ^ ((irow & 7) << 3))];
#pragma unroll
    for (int jt = 0; jt < 16; ++jt) {
      bf16x8 bf = *(const bf16x8*)&Qt[((size_t)b * LQ + jt * 16 + lj) * D_ + kk * 32 + 8 * sl];
      acc[jt] = __builtin_amdgcn_mfma_f32_16x16x32_bf16(af, bf, acc[jt], 0, 0, 0);
    }
  }

  // epilogue: add ca/qb, store fp16 S; keep raw sval in acc
  int ibase = i0 + w_id * 16 + 4 * sl;
  float cavr[4] = {ca_s[w_id * 16 + 4 * sl + 0], ca_s[w_id * 16 + 4 * sl + 1],
                   ca_s[w_id * 16 + 4 * sl + 2], ca_s[w_id * 16 + 4 * sl + 3]};
#pragma unroll
  for (int jt = 0; jt < 16; ++jt) {
    int j = jt * 16 + lj;
    float qbv = qb[b * LQ + j];
#pragma unroll
    for (int r = 0; r < 4; ++r) {
      float sval = acc[jt][r] + cavr[r] + qbv;
      S[((size_t)(b * LC + ibase + r)) * LQ + j] = (_Float16)sval;
      acc[jt][r] = sval;
    }
  }
  // row-softmax stats (axis=2; qmask)
#pragma unroll
  for (int r = 0; r < 4; ++r) {
    float m = -1e38f;
#pragma unroll
    for (int jt = 0; jt < 16; ++jt) m = fmaxf(m, acc[jt][r] + qadds[jt * 16 + lj]);
#pragma unroll
    for (int off = 1; off <= 8; off <<= 1) m = fmaxf(m, __shfl_xor(m, off));
    float s = 0.f;
#pragma unroll
    for (int jt = 0; jt < 16; ++jt) s += __expf(acc[jt][r] + qadds[jt * 16 + lj] - m);
#pragma unroll
    for (int off = 1; off <= 8; off <<= 1) s += __shfl_xor(s, off);
    if (lj == 0) {
      m1[b * LC + ibase + r] = m;
      l1[b * LC + ibase + r] = s;
    }
  }
  // column-softmax partials (axis=1; cmask) over this block's 64 rows
  float cmadd[4];
#pragma unroll
  for (int r = 0; r < 4; ++r) cmadd[r] = (1.0f - cmask[b * LC + ibase + r]) * NEG_INF_;
#pragma unroll
  for (int jt = 0; jt < 16; ++jt) {
    float m = -1e38f, ls = 0.f;
#pragma unroll
    for (int r = 0; r < 4; ++r) {
      float v = acc[jt][r] + cmadd[r];
      float nm = fmaxf(m, v);
      ls = ls * __expf(m - nm) + __expf(v - nm);
      m = nm;
    }
#pragma unroll
    for (int off = 16; off <= 32; off <<= 1) {
      float om = __shfl_xor(m, off);
      float ol = __shfl_xor(ls, off);
      float nm = fmaxf(m, om);
      ls = ls * __expf(m - nm) + ol * __expf(om - nm);
      m = nm;
    }
    if (sl == 0) {
      colM[w_id][jt * 16 + lj] = m;
      colL[w_id][jt * 16 + lj] = ls;
    }
  }
  __syncthreads();
  {
    int j = t;
    float m = -1e38f, ls = 0.f;
#pragma unroll
    for (int wv = 0; wv < 4; ++wv) {
      float mm = colM[wv][j], ll = colL[wv][j];
      float nm = fmaxf(m, mm);
      ls = ls * __expf(m - nm) + ll * __expf(mm - nm);
      m = nm;
    }
    pm[((size_t)b * NBLK + blockIdx.x) * LQ + j] = m;
    pl[((size_t)b * NBLK + blockIdx.x) * LQ + j] = ls;
  }
}

// ---- k_R: Rt[d][j] = sum_i C[d][i]*P2[i][j]  (MFMA; inline colfin merge)
__global__ __launch_bounds__(256, 4) void k_R(const _Float16* __restrict__ S,
                                              const float* __restrict__ C,
                                              const float* __restrict__ cmask,
                                              const float* __restrict__ pm,
                                              const float* __restrict__ pl,
                                              unsigned short* __restrict__ Rt) {
  __shared__ unsigned short Pt[2][32 * 32];  // [j][i] XOR-swizzled
  __shared__ float m2s[32], il2s[32];
  int b = blockIdx.y;
  int j0 = blockIdx.x * 32;
  int t = threadIdx.x;
  if (t < 32) {
    float m = -1e38f, ls = 0.f;
#pragma unroll
    for (int s = 0; s < NBLK; ++s) {
      float mm = pm[((size_t)b * NBLK + s) * LQ + j0 + t];
      float ll = pl[((size_t)b * NBLK + s) * LQ + j0 + t];
      float nm = fmaxf(m, mm);
      ls = ls * __expf(m - nm) + ll * __expf(mm - nm);
      m = nm;
    }
    m2s[t] = m;
    il2s[t] = 1.0f / ls;
  }
  __syncthreads();

  int iL = t >> 3, jc = t & 7;
  int w_id = t >> 6, l = t & 63;
  int sl = l >> 4, lj = l & 15;
  int wbase = w_id * 32;

  f32x4 acc[2][2];
#pragma unroll
  for (int dt = 0; dt < 2; ++dt)
#pragma unroll
    for (int jt = 0; jt < 2; ++jt) acc[dt][jt] = (f32x4){0.f, 0.f, 0.f, 0.f};

  {
    f16x4 sv = *(const f16x4*)&S[((size_t)(b * LC + iL)) * LQ + j0 + 4 * jc];
    float cmadd = (1.0f - cmask[b * LC + iL]) * NEG_INF_;
#pragma unroll
    for (int m = 0; m < 4; ++m) {
      int jl = 4 * jc + m;
      float p = __expf((float)sv[m] + cmadd - m2s[jl]) * il2s[jl];
      Pt[0][jl * 32 + (iL ^ ((jl & 3) << 3))] = bf16b(p);
    }
  }
  __syncthreads();

  for (int kt = 0; kt < 32; ++kt) {
    int cur = kt & 1;
    if (kt < 31) {
      int i0n = (kt + 1) * 32;
      f16x4 sv = *(const f16x4*)&S[((size_t)(b * LC + i0n + iL)) * LQ + j0 + 4 * jc];
      float cmadd = (1.0f - cmask[b * LC + i0n + iL]) * NEG_INF_;
#pragma unroll
      for (int m = 0; m < 4; ++m) {
        int jl = 4 * jc + m;
        float p = __expf((float)sv[m] + cmadd - m2s[jl]) * il2s[jl];
        Pt[cur ^ 1][jl * 32 + (iL ^ ((jl & 3) << 3))] = bf16b(p);
      }
    }
    bf16x8 af[2];
#pragma unroll
    for (int dt = 0; dt < 2; ++dt) {
      int d = wbase + dt * 16 + lj;
      const float* cp = &C[((size_t)b * D_ + d) * LC + kt * 32 + 8 * sl];
      float4 c0 = *(const float4*)cp;
      float4 c1 = *(const float4*)(cp + 4);
      unsigned short ab[8] = {bf16b(c0.x), bf16b(c0.y), bf16b(c0.z), bf16b(c0.w),
                              bf16b(c1.x), bf16b(c1.y), bf16b(c1.z), bf16b(c1.w)};
      af[dt] = *(bf16x8*)ab;
    }
#pragma unroll
    for (int jt = 0; jt < 2; ++jt) {
      bf16x8 bfp = *(const bf16x8*)&Pt[cur][(jt * 16 + lj) * 32 + ((8 * sl) ^ ((lj & 3) << 3))];
#pragma unroll
      for (int dt = 0; dt < 2; ++dt)
        acc[dt][jt] = __builtin_amdgcn_mfma_f32_16x16x32_bf16(af[dt], bfp, acc[dt][jt], 0, 0, 0);
    }
    __syncthreads();
  }

#pragma unroll
  for (int dt = 0; dt < 2; ++dt)
#pragma unroll
    for (int jt = 0; jt < 2; ++jt)
#pragma unroll
      for (int r = 0; r < 4; ++r) {
        int d = wbase + dt * 16 + 4 * sl + r;
        int j = j0 + jt * 16 + lj;
        Rt[((size_t)b * D_ + d) * LQ + j] = bf16b(acc[dt][jt][r]);
      }
}

// ---- k_final: A = Q@P1^T, Bm = Rt@P1^T (per-d rows); out = [Ct|A|Ct*A|Ct*Bm]
__global__ __launch_bounds__(256, 3) void k_final(const _Float16* __restrict__ S,
                                                  const float* __restrict__ C,
                                                  const float* __restrict__ Q,
                                                  const unsigned short* __restrict__ Rt,
                                                  const float* __restrict__ qmask,
                                                  const float* __restrict__ m1,
                                                  const float* __restrict__ l1,
                                                  float* __restrict__ out) {
  __shared__ unsigned short P_lds[2][64 * 32];  // [i][j]
  __shared__ float m1s[64], il1s[64], qadds[256];
  int b = blockIdx.y;
  int i0 = blockIdx.x * 64;
  int t = threadIdx.x;
  if (t < 64) {
    m1s[t] = m1[b * LC + i0 + t];
    il1s[t] = 1.0f / l1[b * LC + i0 + t];
  }
  qadds[t] = (1.0f - qmask[b * LQ + t]) * NEG_INF_;
  __syncthreads();

  int iL = t >> 2, jc = t & 3;
  int w_id = t >> 6, l = t & 63;
  int sl = l >> 4, lj = l & 15;
  int wbase = w_id * 32;
  float m1v = m1s[iL], il1v = il1s[iL];

  f32x4 accQ[2][4], accR[2][4];
#pragma unroll
  for (int dt = 0; dt < 2; ++dt)
#pragma unroll
    for (int it = 0; it < 4; ++it) {
      accQ[dt][it] = (f32x4){0.f, 0.f, 0.f, 0.f};
      accR[dt][it] = (f32x4){0.f, 0.f, 0.f, 0.f};
    }

  {
    f16x8 sv = *(const f16x8*)&S[((size_t)(b * LC + i0 + iL)) * LQ + 8 * jc];
    float qa[8];
    *(float4*)qa = *(const float4*)&qadds[8 * jc];
    *(float4*)(qa + 4) = *(const float4*)&qadds[8 * jc + 4];
    unsigned short pb[8];
#pragma unroll
    for (int e = 0; e < 8; ++e)
      pb[e] = bf16b(__expf((float)sv[e] + qa[e] - m1v) * il1v);
    *(bf16x8*)&P_lds[0][iL * 32 + 8 * jc] = *(bf16x8*)pb;
  }
  __syncthreads();

  for (int s = 0; s < 8; ++s) {
    int cur = s & 1;
    if (s < 7) {
      int j0n = (s + 1) * 32;
      f16x8 sv = *(const f16x8*)&S[((size_t)(b * LC + i0 + iL)) * LQ + j0n + 8 * jc];
      float qa[8];
      *(float4*)qa = *(const float4*)&qadds[j0n + 8 * jc];
      *(float4*)(qa + 4) = *(const float4*)&qadds[j0n + 8 * jc + 4];
      unsigned short pb[8];
#pragma unroll
      for (int e = 0; e < 8; ++e)
        pb[e] = bf16b(__expf((float)sv[e] + qa[e] - m1v) * il1v);
      *(bf16x8*)&P_lds[cur ^ 1][iL * 32 + 8 * jc] = *(bf16x8*)pb;
    }
    int j0c = s * 32;
    bf16x8 aQ[2], aR[2];
#pragma unroll
    for (int dt = 0; dt < 2; ++dt) {
      int d = wbase + dt * 16 + lj;
      const float* qp = &Q[((size_t)b * D_ + d) * LQ + j0c + 8 * sl];
      float4 q0 = *(const float4*)qp;
      float4 q1 = *(const float4*)(qp + 4);
      unsigned short ab[8] = {bf16b(q0.x), bf16b(q0.y), bf16b(q0.z), bf16b(q0.w),
                              bf16b(q1.x), bf16b(q1.y), bf16b(q1.z), bf16b(q1.w)};
      aQ[dt] = *(bf16x8*)ab;
      aR[dt] = *(const bf16x8*)&Rt[((size_t)b * D_ + d) * LQ + j0c + 8 * sl];
    }
#pragma unroll
    for (int it = 0; it < 4; ++it) {
      bf16x8 bP = *(const bf16x8*)&P_lds[cur][(it * 16 + lj) * 32 + 8 * sl];
#pragma unroll
      for (int dt = 0; dt < 2; ++dt) {
        accQ[dt][it] = __builtin_amdgcn_mfma_f32_16x16x32_bf16(aQ[dt], bP, accQ[dt][it], 0, 0, 0);
        accR[dt][it] = __builtin_amdgcn_mfma_f32_16x16x32_bf16(aR[dt], bP, accR[dt][it], 0, 0, 0);
      }
    }
    __syncthreads();
  }

#pragma unroll
  for (int dt = 0; dt < 2; ++dt)
#pragma unroll
    for (int it = 0; it < 4; ++it)
#pragma unroll
      for (int r = 0; r < 4; ++r) {
        int d = wbase + dt * 16 + 4 * sl + r;
        int gi = i0 + it * 16 + lj;
        float c = C[((size_t)b * D_ + d) * LC + gi];
        float a = accQ[dt][it][r];
        float bm = accR[dt][it][r];
        size_t ob = ((size_t)b * 512 + d) * LC + gi;
        out[ob] = c;
        out[ob + (size_t)128 * LC] = a;
        out[ob + (size_t)256 * LC] = c * a;
        out[ob + (size_t)384 * LC] = c * bm;
      }
}

extern "C" void kernel_launch(void* const* d_in, const int* in_sizes, int n_in,
                              void* d_out, int out_size, void* d_ws, size_t ws_size,
                              hipStream_t stream) {
  const float* C = (const float*)d_in[0];
  const float* Q = (const float*)d_in[1];
  const float* cmask = (const float*)d_in[2];
  const float* qmask = (const float*)d_in[3];
  const float* w = (const float*)d_in[4];
  float* out = (float*)d_out;
  float* ws = (float*)d_ws;

  // ws layout (~42.6 MB): small f32 first, bf16/fp16 last (S last)
  float* qb = ws;                                   // B*LQ
  float* m1 = qb + (size_t)B_ * LQ;                 // B*LC
  float* l1 = m1 + (size_t)B_ * LC;                 // B*LC
  float* pm = l1 + (size_t)B_ * LC;                 // B*NBLK*LQ
  float* pl = pm + (size_t)B_ * NBLK * LQ;          // B*NBLK*LQ
  unsigned short* Qt = (unsigned short*)(pl + (size_t)B_ * NBLK * LQ);  // B*LQ*D
  unsigned short* Rt = Qt + (size_t)B_ * LQ * D_;   // B*D*LQ
  _Float16* S = (_Float16*)(Rt + (size_t)B_ * D_ * LQ);  // B*LC*LQ fp16

  k_prep_q<<<dim3(LQ / 64, B_), 256, 0, stream>>>(Q, w, Qt, qb);
  k_S<<<dim3(LC / 64, B_), 256, 0, stream>>>(C, Qt, w, qb, qmask, cmask, S, m1, l1, pm, pl);
  k_R<<<dim3(LQ / 32, B_), 256, 0, stream>>>(S, C, cmask, pm, pl, Rt);
  k_final<<<dim3(LC / 64, B_), 256, 0, stream>>>(S, C, Q, Rt, qmask, m1, l1, out);
}